// Round 1
// baseline (463.642 us; speedup 1.0000x reference)
//
#include <hip/hip_runtime.h>
#include <hip/hip_bf16.h>

// EnergyDecoder fused kernel for MI355X (gfx950).
// Strategy: single read of h_cat (268 MB, the irreducible traffic), fp16 MFMA
// for the fused two-MLP layer-1 GEMM (M=262144, N=256, K=256), in-kernel
// layer-2 reduction + full energy epilogue + atomic [B,4] accumulation.
// Target: HBM-bound at ~45-60 us.

typedef _Float16 half8 __attribute__((ext_vector_type(8)));
typedef float    f32x4 __attribute__((ext_vector_type(4)));
typedef unsigned int u32x4 __attribute__((ext_vector_type(4)));

#define NLIG 64
#define NTGT 512
#define KDIM 256      // 2*C
#define NDIM 256      // both MLPs' layer-1 columns (A: 0..127, B: 128..255)
#define BM   128      // rows per block (consecutive (l,t) pairs)
#define BK   32       // K-step
#define NKS  8        // K-steps (256/32)
#define RS   40       // padded LDS row stride in halves (32 + 8) -> conflict-free b128

// ---------------------------------------------------------------------------
// Prep: Wt[n][k] = fp16(W1[k][n]) for the combined weight (WA1 | WB1),
// so B-operand fragments are 8 contiguous k per lane (ds_read_b128).
// Also zero the 32-float output (harness poisons d_out with 0xAA each launch).
// ---------------------------------------------------------------------------
__global__ void ed_prep_kernel(const float* __restrict__ WA1,
                               const float* __restrict__ WB1,
                               _Float16* __restrict__ wt,
                               float* __restrict__ out) {
    int gid = blockIdx.x * 256 + threadIdx.x;   // 64 blocks x 256 thr = 16384
    int c   = gid >> 6;                          // k index 0..255
    int n0  = (gid & 63) * 4;                    // n quad 0..252
    const float* src = (n0 < 128) ? (WA1 + c * 128 + n0)
                                  : (WB1 + c * 128 + (n0 - 128));
    f32x4 v = *(const f32x4*)src;                // coalesced read
#pragma unroll
    for (int j = 0; j < 4; ++j)
        wt[(size_t)(n0 + j) * 256 + c] = (_Float16)v[j];
    if (gid < 32) out[gid] = 0.0f;
}

// ---------------------------------------------------------------------------
// Main fused kernel. Grid: 2048 blocks = (b, l, t-tile) with 128 rows each.
// 512 threads = 8 waves arranged 2(M) x 4(N); per-wave 64x64 output tile via
// 4x4 fragments of mfma_f32_16x16x32_f16.
// ---------------------------------------------------------------------------
__global__ __launch_bounds__(512, 4) void ed_main_kernel(
    const float* __restrict__ lig_pos, const float* __restrict__ tgt_pos,
    const float* __restrict__ lig_vdw, const float* __restrict__ tgt_vdw,
    const float* __restrict__ lig_nm,  const float* __restrict__ tgt_nm,
    const float* __restrict__ ind,     const float* __restrict__ rotor,
    const float* __restrict__ h,       const _Float16* __restrict__ wt,
    const float* __restrict__ bA1, const float* __restrict__ WA2,
    const float* __restrict__ bA2,
    const float* __restrict__ bB1, const float* __restrict__ WB2,
    const float* __restrict__ bB2,
    const float* __restrict__ hbc, const float* __restrict__ hpc,
    const float* __restrict__ rtc,
    float* __restrict__ out)
{
    __shared__ _Float16 sA[2][BM * RS];      // 20480 B
    __shared__ _Float16 sW[2][NDIM * RS];    // 40960 B
    __shared__ float    sRed[4][BM];         //  2048 B
    __shared__ float    sFin[32];

    const int tid  = threadIdx.x;
    const int lane = tid & 63;
    const int wid  = tid >> 6;
    const int wm   = wid >> 2;   // 0..1  (64-row half)
    const int wn   = wid & 3;    // 0..3  (64-col slice; 0,1 -> MLP-A, 2,3 -> MLP-B)
    const int lr   = lane & 15;
    const int lg   = lane >> 4;

    const int bx = blockIdx.x;           // 0..2047
    const int b  = bx >> 8;              // 256 blocks per batch
    const int l  = (bx >> 2) & 63;
    const int t0 = (bx & 3) * BM;

    const float* hA = h + (size_t)bx * (BM * KDIM);

    // staging assignments
    const int arow = tid >> 2;           // 0..127 : h row within tile
    const int akq  = (tid & 3) * 8;      // k offset (8 floats)
    const int wrow = tid >> 1;           // 0..255 : Wt row (n)
    const int whq  = (tid & 1) * 16;     // k offset (16 halves)

    f32x4 a0, a1;
    u32x4 w0, w1;

    // prologue: load + write tile 0 into buffer 0
    {
        const float* pa = hA + (size_t)arow * KDIM + akq;
        a0 = *(const f32x4*)pa;
        a1 = *(const f32x4*)(pa + 4);
        const _Float16* pw = wt + wrow * KDIM + whq;
        w0 = *(const u32x4*)pw;
        w1 = *(const u32x4*)(pw + 8);
        half8 hv;
#pragma unroll
        for (int j = 0; j < 4; ++j) hv[j] = (_Float16)a0[j];
#pragma unroll
        for (int j = 0; j < 4; ++j) hv[4 + j] = (_Float16)a1[j];
        *(half8*)&sA[0][arow * RS + akq] = hv;
        *(u32x4*)&sW[0][wrow * RS + whq]     = w0;
        *(u32x4*)&sW[0][wrow * RS + whq + 8] = w1;
    }

    f32x4 acc[4][4];
#pragma unroll
    for (int m = 0; m < 4; ++m)
#pragma unroll
        for (int n = 0; n < 4; ++n) acc[m][n] = 0;

    for (int ks = 0; ks < NKS; ++ks) {
        const int bf = ks & 1;
        __syncthreads();   // buffer bf writes visible block-wide
        // issue next-tile global loads right after the barrier: they hide
        // under the MFMA phase, consumed by the ds_writes at iteration end.
        if (ks + 1 < NKS) {
            const float* pa = hA + (size_t)arow * KDIM + (ks + 1) * BK + akq;
            a0 = *(const f32x4*)pa;
            a1 = *(const f32x4*)(pa + 4);
            const _Float16* pw = wt + wrow * KDIM + (ks + 1) * BK + whq;
            w0 = *(const u32x4*)pw;
            w1 = *(const u32x4*)(pw + 8);
        }
        // compute on buffer bf
        half8 af[4], wf[4];
#pragma unroll
        for (int m = 0; m < 4; ++m)
            af[m] = *(const half8*)&sA[bf][(wm * 64 + m * 16 + lr) * RS + lg * 8];
#pragma unroll
        for (int n = 0; n < 4; ++n)
            wf[n] = *(const half8*)&sW[bf][(wn * 64 + n * 16 + lr) * RS + lg * 8];
#pragma unroll
        for (int m = 0; m < 4; ++m)
#pragma unroll
            for (int n = 0; n < 4; ++n)
                acc[m][n] = __builtin_amdgcn_mfma_f32_16x16x32_f16(
                    af[m], wf[n], acc[m][n], 0, 0, 0);
        // stage next tile into the other buffer (safe: all reads of that
        // buffer completed before the barrier above)
        if (ks + 1 < NKS) {
            const int nb = bf ^ 1;
            half8 hv;
#pragma unroll
            for (int j = 0; j < 4; ++j) hv[j] = (_Float16)a0[j];
#pragma unroll
            for (int j = 0; j < 4; ++j) hv[4 + j] = (_Float16)a1[j];
            *(half8*)&sA[nb][arow * RS + akq] = hv;
            *(u32x4*)&sW[nb][wrow * RS + whq]     = w0;
            *(u32x4*)&sW[nb][wrow * RS + whq + 8] = w1;
        }
    }

    // ---- layer-2: out(row) = sum_col relu(x + b1[col]) * w2[col] ----------
    float cb[4], cw[4];
#pragma unroll
    for (int n = 0; n < 4; ++n) {
        int col = wn * 64 + n * 16 + lr;
        if (col < 128) { cb[n] = bA1[col];       cw[n] = WA2[col]; }
        else           { cb[n] = bB1[col - 128]; cw[n] = WB2[col - 128]; }
    }
#pragma unroll
    for (int m = 0; m < 4; ++m) {
#pragma unroll
        for (int r = 0; r < 4; ++r) {
            float p = 0.f;
#pragma unroll
            for (int n = 0; n < 4; ++n)
                p += fmaxf(acc[m][n][r] + cb[n], 0.f) * cw[n];
            // reduce across the 16 lanes holding this row's 16 columns
            p += __shfl_xor(p, 1);
            p += __shfl_xor(p, 2);
            p += __shfl_xor(p, 4);
            p += __shfl_xor(p, 8);
            if (lr == 0)
                sRed[wn][wm * 64 + m * 16 + lg * 4 + r] = p;
        }
    }
    __syncthreads();

    // ---- per-row energy epilogue (threads 0..127, one row each) -----------
    float e0 = 0.f, e1 = 0.f, e2 = 0.f, e3 = 0.f;
    if (tid < BM) {
        const int t = t0 + tid;
        float mlpA = sRed[0][tid] + sRed[1][tid] + bA2[0];
        float mlpB = sRed[2][tid] + sRed[3][tid] + bB2[0];
        float Bp = tanhf(mlpB) * 0.2f;                      // DEV_VDW_RADIUS
        float lv = lig_vdw[b * NLIG + l];
        float tv = tgt_vdw[b * NTGT + t];
        float dx = lig_pos[(b * NLIG + l) * 3 + 0] - tgt_pos[(b * NTGT + t) * 3 + 0];
        float dy = lig_pos[(b * NLIG + l) * 3 + 1] - tgt_pos[(b * NTGT + t) * 3 + 1];
        float dz = lig_pos[(b * NLIG + l) * 3 + 2] - tgt_pos[(b * NTGT + t) * 3 + 2];
        float dm = sqrtf(dx * dx + dy * dy + dz * dz + 1e-10f);
        if (dm < 0.5f) dm = 1e10f;                          // DM_MIN mask
        float dm0  = lv + tv + Bp;
        float dm0c = (dm0 < 1e-4f) ? 1.0f : dm0;
        float qr = dm0c / dm;
        float q2 = qr * qr;
        float r6 = q2 * q2 * q2;                            // (dm0c/dm)^6
        float ve = fminf(r6 * r6 - 2.0f * r6, 100.0f);
        ve *= lig_nm[b * NLIG + l] * tgt_nm[b * NTGT + t];
        float Av = 1.0f / (1.0f + expf(-mlpA)) * (float)(0.0356 - 0.0178) + 0.0178f;
        e0 = Av * ve;                                       // vdw
        float d = dm - dm0;
        const float* ib = ind + (size_t)b * 3 * NLIG * NTGT + (size_t)l * NTGT + t;
        float i0 = ib[0];
        float i1 = ib[NLIG * NTGT];
        float i2 = ib[2 * NLIG * NTGT];
        e1 = fminf(fmaxf(d * i0 / -0.7f, 0.f), 1.f);        // hbond
        e2 = fminf(fmaxf(d * i1 / -0.7f, 0.f), 1.f);        // metal
        e3 = fminf(fmaxf((-d + 1.5f) * i2, 0.f), 1.f);      // hydrophobic
    }
#pragma unroll
    for (int off = 32; off > 0; off >>= 1) {
        e0 += __shfl_down(e0, off);
        e1 += __shfl_down(e1, off);
        e2 += __shfl_down(e2, off);
        e3 += __shfl_down(e3, off);
    }
    if (lane == 0) {
        sFin[wid * 4 + 0] = e0; sFin[wid * 4 + 1] = e1;
        sFin[wid * 4 + 2] = e2; sFin[wid * 4 + 3] = e3;
    }
    __syncthreads();
    if (tid == 0) {
        float s0 = 0, s1 = 0, s2 = 0, s3 = 0;
#pragma unroll
        for (int w = 0; w < 8; ++w) {
            s0 += sFin[w * 4 + 0]; s1 += sFin[w * 4 + 1];
            s2 += sFin[w * 4 + 2]; s3 += sFin[w * 4 + 3];
        }
        float hc = hbc[0], pc = hpc[0], rc = rtc[0];
        float inv = 1.0f / (1.0f + rc * rc * rotor[b]);
        __hip_atomic_fetch_add(&out[b * 4 + 0], s0 * inv,
                               __ATOMIC_RELAXED, __HIP_MEMORY_SCOPE_AGENT);
        __hip_atomic_fetch_add(&out[b * 4 + 1], -(hc * hc) * s1 * inv,
                               __ATOMIC_RELAXED, __HIP_MEMORY_SCOPE_AGENT);
        __hip_atomic_fetch_add(&out[b * 4 + 2], -(hc * hc) * s2 * inv,
                               __ATOMIC_RELAXED, __HIP_MEMORY_SCOPE_AGENT);
        __hip_atomic_fetch_add(&out[b * 4 + 3], -(pc * pc) * s3 * inv,
                               __ATOMIC_RELAXED, __HIP_MEMORY_SCOPE_AGENT);
    }
}

extern "C" void kernel_launch(void* const* d_in, const int* in_sizes, int n_in,
                              void* d_out, int out_size, void* d_ws, size_t ws_size,
                              hipStream_t stream) {
    (void)in_sizes; (void)n_in; (void)out_size; (void)ws_size;
    const float* lig_pos = (const float*)d_in[0];
    const float* tgt_pos = (const float*)d_in[1];
    const float* lig_vdw = (const float*)d_in[2];
    const float* tgt_vdw = (const float*)d_in[3];
    const float* lig_nm  = (const float*)d_in[4];
    const float* tgt_nm  = (const float*)d_in[5];
    const float* ind     = (const float*)d_in[6];
    const float* rotor   = (const float*)d_in[7];
    const float* h       = (const float*)d_in[8];
    const float* WA1     = (const float*)d_in[9];
    const float* bA1     = (const float*)d_in[10];
    const float* WA2     = (const float*)d_in[11];
    const float* bA2     = (const float*)d_in[12];
    const float* WB1     = (const float*)d_in[13];
    const float* bB1     = (const float*)d_in[14];
    const float* WB2     = (const float*)d_in[15];
    const float* bB2     = (const float*)d_in[16];
    const float* hbc     = (const float*)d_in[17];
    const float* hpc     = (const float*)d_in[18];
    const float* rtc     = (const float*)d_in[19];
    float* out  = (float*)d_out;
    _Float16* wt = (_Float16*)d_ws;   // 256*256 fp16 = 128 KiB scratch

    ed_prep_kernel<<<dim3(64), dim3(256), 0, stream>>>(WA1, WB1, wt, out);
    ed_main_kernel<<<dim3(2048), dim3(512), 0, stream>>>(
        lig_pos, tgt_pos, lig_vdw, tgt_vdw, lig_nm, tgt_nm, ind, rotor, h, wt,
        bA1, WA2, bA2, bB1, WB2, bB2, hbc, hpc, rtc, out);
}